// Round 5
// baseline (154.396 us; speedup 1.0000x reference)
//
#include <hip/hip_runtime.h>
#include <hip/hip_bf16.h>

#define Bb   4
#define Hh   16
#define Ss   2048
#define Dd   128
#define QBLK 128
#define KVB  64

typedef __attribute__((ext_vector_type(8))) short bf16x8;
typedef __attribute__((ext_vector_type(4))) float f32x4;
typedef __attribute__((ext_vector_type(4))) float fvec4;
typedef __attribute__((ext_vector_type(2))) unsigned u32x2;
typedef __attribute__((ext_vector_type(4))) unsigned u32x4;

__device__ __forceinline__ unsigned pk2(float a, float b) {
    __hip_bfloat162 h = __float22bfloat162_rn(make_float2(a, b));
    unsigned u; __builtin_memcpy(&u, &h, 4); return u;
}

typedef const __attribute__((address_space(1))) char* gas_t;
typedef __attribute__((address_space(3))) char* las_t;
__device__ __forceinline__ void gld16(const void* g, void* l) {
    __builtin_amdgcn_global_load_lds((gas_t)g, (las_t)l, 16, 0, 0);
}

// ---------- prepass A: K fp32 -> bf16 same layout ----------
__global__ __launch_bounds__(256) void cvtk_kernel(const float* __restrict__ K,
                                                   short* __restrict__ Kb) {
    size_t i = ((size_t)blockIdx.x * 256 + threadIdx.x) * 8;
    fvec4 a = ((const fvec4*)(K + i))[0];
    fvec4 b = ((const fvec4*)(K + i))[1];
    u32x4 u;
    u[0] = pk2(a[0], a[1]); u[1] = pk2(a[2], a[3]);
    u[2] = pk2(b[0], b[1]); u[3] = pk2(b[2], b[3]);
    *(u32x4*)(Kb + i) = u;
}

// ---------- prepass B: V fp32 [bh][s][d] -> bf16 [bh][d][s] + partial col sums ----------
__global__ __launch_bounds__(256) void cvtv_kernel(const float* __restrict__ V,
                                                   short* __restrict__ Vt,
                                                   float* __restrict__ part) {
    __shared__ short Lt[128 * 136];
    __shared__ fvec4 red[256];
    const int bh = blockIdx.x >> 4, ch = blockIdx.x & 15;
    const int tid = threadIdx.x;
    const float* src = V + ((size_t)bh * Ss + ch * 128) * Dd;
    const int c4 = tid & 31, s0 = tid >> 5;
    fvec4 acc = {0.f, 0.f, 0.f, 0.f};
    #pragma unroll
    for (int i = 0; i < 16; ++i) {
        int s = s0 + 8 * i;
        fvec4 v = ((const fvec4*)(src + (size_t)s * Dd))[c4];
        acc += v;
        u32x2 p; p[0] = pk2(v[0], v[1]); p[1] = pk2(v[2], v[3]);
        *(u32x2*)&Lt[s * 136 + c4 * 4] = p;
    }
    red[tid] = acc;
    __syncthreads();
    for (int off = 128; off >= 32; off >>= 1) {
        if (tid < off) red[tid] += red[tid + off];
        __syncthreads();
    }
    if (tid < 32) ((fvec4*)(part + (size_t)blockIdx.x * Dd))[tid] = red[tid];
    #pragma unroll
    for (int i = 0; i < 8; ++i) {
        int g2 = tid + 256 * i;
        int d = g2 >> 4, sg = g2 & 15;
        short tmp[8];
        #pragma unroll
        for (int j = 0; j < 8; ++j) tmp[j] = Lt[(sg * 8 + j) * 136 + d];
        u32x4 u; __builtin_memcpy(&u, tmp, 16);
        *(u32x4*)(Vt + ((size_t)(bh * Dd + d)) * Ss + ch * 128 + sg * 8) = u;
    }
}

// ---------- fallback partial V sums ----------
__global__ __launch_bounds__(256) void vpart_kernel(const float* __restrict__ V,
                                                    float* __restrict__ part) {
    int blk = blockIdx.x, bh = blk >> 3, ch = blk & 7;
    int tid = threadIdx.x, d4 = tid & 31, rg = tid >> 5;
    const fvec4* p = (const fvec4*)(V + ((size_t)bh * Ss + ch * 256) * Dd) + d4;
    fvec4 s = {0.f, 0.f, 0.f, 0.f};
    for (int rr = 0; rr < 32; ++rr) s += p[(size_t)(rg * 32 + rr) * 32];
    __shared__ fvec4 red[256];
    red[tid] = s;
    __syncthreads();
    for (int off = 128; off >= 32; off >>= 1) {
        if (tid < off) red[tid] += red[tid + off];
        __syncthreads();
    }
    if (tid < 32) ((fvec4*)(part + (size_t)blk * Dd))[tid] = red[tid];
}

// ---------- combine partials -> vmean ----------
__global__ __launch_bounds__(128) void vcomb_kernel(const float* __restrict__ part,
                                                    float* __restrict__ vm, int nch) {
    int bh = blockIdx.x, d = threadIdx.x;
    float s = 0.f;
    for (int c = 0; c < nch; ++c) s += part[(size_t)(bh * nch + c) * Dd + d];
    vm[bh * Dd + d] = s * (1.0f / 2048.0f);
}

// ================= 8-wave flash attention: even/odd KV split ==================
// LDS 160KB: [0,64K) K stage (grp,buf); [64K,128K) V stage; [128K,160K) Ps.
__global__ __launch_bounds__(512, 2) void attn8_kernel(
    const float* __restrict__ Qg, const short* __restrict__ Kbf,
    const short* __restrict__ Vtb, const int* __restrict__ slen,
    const float* __restrict__ vmean, float* __restrict__ Og)
{
    __shared__ __align__(16) char smem[163840];

    const int bid = blockIdx.x;
    const int qslot = bid >> 6, r = bid & 63;
    const int qt = 15 - qslot;                         // deepest q-tiles first
    const int b  = (r >> 3) & 3;                       // every batch on every XCD
    const int h  = (r & 7) | ((r >> 5) << 3);
    const int bh = b * 16 + h;                         // (b,h)'s q-tiles share XCD
    const int len = slen[b];
    const int q0 = qt * QBLK;
    const int tid = threadIdx.x;

    if (q0 >= len) {                                   // fully-invalid: rows = mean(V)
        const fvec4* vm4 = (const fvec4*)(vmean + bh * Dd);
        fvec4 val = vm4[tid & 31];
        float* ob = Og + ((size_t)bh * Ss + q0) * Dd;
        int r0 = tid >> 5;
        #pragma unroll
        for (int i = 0; i < 8; ++i)
            ((fvec4*)(ob + (size_t)(r0 + 16 * i) * Dd))[tid & 31] = val;
        return;
    }

    const int w = tid >> 6, lane = tid & 63;
    const int grp = w >> 2, wg = w & 3;                // group A=0 even tiles, B=1 odd
    const int g = lane >> 4, qc = lane & 15;
    const int qw0 = q0 + wg * 32;
    const bool wave_active = (qw0 < len);

    const int kv_end   = min(q0 + QBLK, len);
    const int kv_end_w = min(qw0 + 32, kv_end);
    const int nt  = (kv_end + KVB - 1) >> 6;
    const int itn = (nt + 1) >> 1;

    char* const KgB = smem + grp * 32768;              // this group's K bufs (2x16K)
    char* const VgB = smem + 65536 + grp * 32768;
    char* const PsB = smem + 131072 + w * 4096;

    int CK[4], CV[4];
    const char* KbhB = (const char*)Kbf + (size_t)bh * Ss * 256;
    const char* VbhB = (const char*)Vtb + (size_t)bh * Dd * (Ss * 2);
    #pragma unroll
    for (int i = 0; i < 4; ++i) {
        int krow = wg * 16 + i * 4 + (lane >> 4);
        int jK = lane & 15;
        int jKs = (jK & 8) | ((jK & 7) ^ (krow & 7));
        CK[i] = krow * 256 + jKs * 16;
        int d = wg * 32 + i * 8 + (lane >> 3);
        int jV = lane & 7;
        CV[i] = d * 4096 + (jV ^ (d & 7)) * 16;
    }

    #define GISSUE8(tile_, buf_) do {                                                  \
        size_t kb_ = (size_t)(tile_) * (KVB * 256);                                    \
        size_t vb_ = (size_t)(tile_) * (KVB * 2);                                      \
        _Pragma("unroll")                                                              \
        for (int i_ = 0; i_ < 4; ++i_)                                                 \
            gld16(KbhB + kb_ + CK[i_], KgB + (buf_) * 16384 + wg * 4096 + i_ * 1024);  \
        _Pragma("unroll")                                                              \
        for (int i_ = 0; i_ < 4; ++i_)                                                 \
            gld16(VbhB + vb_ + CV[i_], VgB + (buf_) * 16384 + wg * 4096 + i_ * 1024);  \
    } while (0)

    if (grp < nt) GISSUE8(grp, 0);                     // tile 0 (A) / tile 1 (B)

    const float SC = 0.12752870368768582f;             // log2(e)/sqrt(128)
    bf16x8 qf[2][4];
    #pragma unroll
    for (int t2 = 0; t2 < 2; ++t2) {
        const float* qrow = Qg + ((size_t)bh * Ss + (qw0 + 16 * t2 + qc)) * Dd;
        #pragma unroll
        for (int kc = 0; kc < 4; ++kc) {
            const fvec4* p = (const fvec4*)(qrow + kc * 32 + g * 8);
            fvec4 a = p[0], bv = p[1];
            unsigned* fu = (unsigned*)&qf[t2][kc];
            fu[0] = pk2(a[0] * SC, a[1] * SC);
            fu[1] = pk2(a[2] * SC, a[3] * SC);
            fu[2] = pk2(bv[0] * SC, bv[1] * SC);
            fu[3] = pk2(bv[2] * SC, bv[3] * SC);
        }
    }

    asm volatile("s_waitcnt vmcnt(0)" ::: "memory");
    __syncthreads();

    f32x4 o[2][8];
    #pragma unroll
    for (int t2 = 0; t2 < 2; ++t2)
        #pragma unroll
        for (int dt = 0; dt < 8; ++dt) o[t2][dt] = (f32x4){0.f, 0.f, 0.f, 0.f};
    float m_[2]   = {-3e38f, -3e38f};
    float lsum[2] = {0.f, 0.f};

    for (int i = 0; i < itn; ++i) {
        const int t = 2 * i + grp;
        const int kv0 = t * KVB;
        const int tn = t + 2;
        const bool active = wave_active && (t < nt) && (kv0 < kv_end_w);

        if (tn < nt) GISSUE8(tn, (i + 1) & 1);         // DMA flies under compute

        if (active) {
            const char* KsB = KgB + (i & 1) * 16384;
            const char* VtB = VgB + (i & 1) * 16384;
            f32x4 sa[2][4];
            #pragma unroll
            for (int t2 = 0; t2 < 2; ++t2)
                #pragma unroll
                for (int mt = 0; mt < 4; ++mt) sa[t2][mt] = (f32x4){0.f, 0.f, 0.f, 0.f};
            __builtin_amdgcn_s_setprio(1);
            #pragma unroll
            for (int mt = 0; mt < 4; ++mt) {
                int row = mt * 16 + qc;
                bf16x8 kf[4];
                #pragma unroll
                for (int kc = 0; kc < 4; ++kc) {
                    int jb = kc * 4 + g;
                    int js = (jb & 8) | ((jb & 7) ^ (row & 7));
                    kf[kc] = *(const bf16x8*)(KsB + row * 256 + js * 16);
                }
                #pragma unroll
                for (int t2 = 0; t2 < 2; ++t2)
                    #pragma unroll
                    for (int kc = 0; kc < 4; ++kc)
                        sa[t2][mt] = __builtin_amdgcn_mfma_f32_16x16x32_bf16(
                            kf[kc], qf[t2][kc], sa[t2][mt], 0, 0, 0);
            }
            __builtin_amdgcn_s_setprio(0);

            // ---- mask + online softmax (defer-max) ----
            #pragma unroll
            for (int t2 = 0; t2 < 2; ++t2) {
                const int qrow = qw0 + 16 * t2 + qc;
                const bool full = (kv0 + KVB - 1) <= (qw0 + 16 * t2);
                if (!full) {
                    #pragma unroll
                    for (int mt = 0; mt < 4; ++mt)
                        #pragma unroll
                        for (int rr = 0; rr < 4; ++rr) {
                            int kk = kv0 + mt * 16 + g * 4 + rr;
                            if (kk > qrow) sa[t2][mt][rr] = -3e38f;
                        }
                }
                float tm = sa[t2][0][0];
                #pragma unroll
                for (int mt = 0; mt < 4; ++mt)
                    #pragma unroll
                    for (int rr = 0; rr < 4; ++rr) tm = fmaxf(tm, sa[t2][mt][rr]);
                tm = fmaxf(tm, __shfl_xor(tm, 16));
                tm = fmaxf(tm, __shfl_xor(tm, 32));
                if (__any(tm > m_[t2] + 8.0f)) {
                    float mnew = fmaxf(m_[t2], tm);
                    float al = exp2f(m_[t2] - mnew);
                    m_[t2] = mnew;
                    lsum[t2] *= al;
                    #pragma unroll
                    for (int rr = 0; rr < 4; ++rr) {
                        float alr = __shfl(al, g * 4 + rr);
                        #pragma unroll
                        for (int dt = 0; dt < 8; ++dt) o[t2][dt][rr] *= alr;
                    }
                }
                float mref = m_[t2];
                float ls = 0.f;
                int prow = t2 * 16 + qc;
                int pswz = (prow & 7) << 4;
                #pragma unroll
                for (int mt = 0; mt < 4; ++mt) {
                    f32x4 p;
                    #pragma unroll
                    for (int rr = 0; rr < 4; ++rr)
                        p[rr] = exp2f(sa[t2][mt][rr] - mref);
                    ls += (p[0] + p[1]) + (p[2] + p[3]);
                    u32x2 pw;
                    pw[0] = pk2(p[0], p[1]);
                    pw[1] = pk2(p[2], p[3]);
                    *(u32x2*)(PsB + ((prow * 128 + mt * 32 + g * 8) ^ pswz)) = pw;
                }
                lsum[t2] += ls;
            }

            // ---- PV ----
            bf16x8 ap[2][2];
            #pragma unroll
            for (int t2 = 0; t2 < 2; ++t2) {
                int prow = t2 * 16 + qc;
                int pswz = (prow & 7) << 4;
                #pragma unroll
                for (int c = 0; c < 2; ++c)
                    ap[t2][c] = *(const bf16x8*)(PsB + ((prow * 128 + c * 64 + g * 16) ^ pswz));
            }
            __builtin_amdgcn_s_setprio(1);
            #pragma unroll
            for (int dt = 0; dt < 8; ++dt) {
                int d = dt * 16 + qc;
                #pragma unroll
                for (int c = 0; c < 2; ++c) {
                    int js = (c * 4 + g) ^ (d & 7);
                    bf16x8 bfv = *(const bf16x8*)(VtB + d * 128 + js * 16);
                    #pragma unroll
                    for (int t2 = 0; t2 < 2; ++t2)
                        o[t2][dt] = __builtin_amdgcn_mfma_f32_16x16x32_bf16(
                            ap[t2][c], bfv, o[t2][dt], 0, 0, 0);
                }
            }
            __builtin_amdgcn_s_setprio(0);
        }

        asm volatile("s_waitcnt vmcnt(0)" ::: "memory");
        __syncthreads();
    }
    #undef GISSUE8

    // ---- merge group B into group A via freed stage LDS ----
    __syncthreads();
    float* dumpO  = (float*)smem;                      // 64 KB: strip*16KB
    float* dumpML = (float*)(smem + 65536);            // strip*64 floats
    if (grp == 1) {
        #pragma unroll
        for (int t2 = 0; t2 < 2; ++t2) {
            float L = lsum[t2];
            L += __shfl_xor(L, 16);
            L += __shfl_xor(L, 32);
            if (lane < 16) {
                dumpML[wg * 64 + t2 * 32 + qc * 2 + 0] = m_[t2];
                dumpML[wg * 64 + t2 * 32 + qc * 2 + 1] = L;
            }
            #pragma unroll
            for (int dt = 0; dt < 8; ++dt)
                *(f32x4*)(dumpO + wg * 4096 + (t2 * 8 + dt) * 256 + lane * 4) = o[t2][dt];
        }
    }
    __syncthreads();
    if (grp == 1) return;

    bool needvm = (qw0 + 32 > len);
    float vmv[8];
    #pragma unroll
    for (int dt = 0; dt < 8; ++dt)
        vmv[dt] = needvm ? vmean[bh * Dd + dt * 16 + qc] : 0.f;

    #pragma unroll
    for (int t2 = 0; t2 < 2; ++t2) {
        float mB = dumpML[wg * 64 + t2 * 32 + qc * 2 + 0];
        float lB = dumpML[wg * 64 + t2 * 32 + qc * 2 + 1];
        float LA = lsum[t2];
        LA += __shfl_xor(LA, 16);
        LA += __shfl_xor(LA, 32);
        float mM = fmaxf(m_[t2], mB);
        float aA = exp2f(m_[t2] - mM);
        float aB = exp2f(mB - mM);
        float invL = 1.0f / (LA * aA + lB * aB);
        f32x4 obv[8];
        #pragma unroll
        for (int dt = 0; dt < 8; ++dt)
            obv[dt] = *(const f32x4*)(dumpO + wg * 4096 + (t2 * 8 + dt) * 256 + lane * 4);
        #pragma unroll
        for (int rr = 0; rr < 4; ++rr) {
            float aAr = __shfl(aA, g * 4 + rr);
            float aBr = __shfl(aB, g * 4 + rr);
            float ivr = __shfl(invL, g * 4 + rr);
            int rowg = qw0 + t2 * 16 + g * 4 + rr;
            float* orow = Og + ((size_t)bh * Ss + rowg) * Dd + qc;
            #pragma unroll
            for (int dt = 0; dt < 8; ++dt) {
                float val = (o[t2][dt][rr] * aAr + obv[dt][rr] * aBr) * ivr;
                if (rowg >= len) val = vmv[dt];
                orow[dt * 16] = val;
            }
        }
    }
}

// ================= fallback (ws too small): 4-wave in-kernel cvt =================
__global__ __launch_bounds__(256, 2) void attn_fb_kernel(
    const float* __restrict__ Qg, const float* __restrict__ Kg,
    const float* __restrict__ Vg, const int* __restrict__ slen,
    const float* __restrict__ vmean, float* __restrict__ Og)
{
    __shared__ __align__(16) short Ks[KVB * Dd];
    __shared__ __align__(16) short Vt[Dd * KVB];
    __shared__ __align__(16) short Ps[4 * 32 * KVB];

    const int bid = blockIdx.x;
    const int qslot = bid >> 6, r = bid & 63;
    const int qt = 15 - qslot;
    const int b  = (r >> 3) & 3;
    const int h  = (r & 7) | ((r >> 5) << 3);
    const int bh = b * 16 + h;
    const int len = slen[b];
    const int q0 = qt * QBLK;
    const int tid = threadIdx.x;

    if (q0 >= len) {
        const fvec4* vm4 = (const fvec4*)(vmean + bh * Dd);
        fvec4 val = vm4[tid & 31];
        float* ob = Og + ((size_t)bh * Ss + q0) * Dd;
        int r0 = tid >> 5;
        #pragma unroll
        for (int i = 0; i < 16; ++i)
            ((fvec4*)(ob + (size_t)(r0 + 8 * i) * Dd))[tid & 31] = val;
        return;
    }

    const int w = tid >> 6, lane = tid & 63;
    const int g = lane >> 4, qc = lane & 15;
    const int qw0 = q0 + w * 32;
    const bool wave_active = (qw0 < len);

    const int kv_end   = min(q0 + QBLK, len);
    const int kv_end_w = min(qw0 + 32, kv_end);
    const int nt = (kv_end + KVB - 1) >> 6;

    const float SC = 0.12752870368768582f;
    bf16x8 qf[2][4];
    #pragma unroll
    for (int t2 = 0; t2 < 2; ++t2) {
        const float* qrow = Qg + ((size_t)bh * Ss + (qw0 + 16 * t2 + qc)) * Dd;
        #pragma unroll
        for (int kc = 0; kc < 4; ++kc) {
            const fvec4* p = (const fvec4*)(qrow + kc * 32 + g * 8);
            fvec4 a = p[0], bv = p[1];
            unsigned* fu = (unsigned*)&qf[t2][kc];
            fu[0] = pk2(a[0] * SC, a[1] * SC);
            fu[1] = pk2(a[2] * SC, a[3] * SC);
            fu[2] = pk2(bv[0] * SC, bv[1] * SC);
            fu[3] = pk2(bv[2] * SC, bv[3] * SC);
        }
    }

    f32x4 o[2][8];
    #pragma unroll
    for (int t2 = 0; t2 < 2; ++t2)
        #pragma unroll
        for (int dt = 0; dt < 8; ++dt) o[t2][dt] = (f32x4){0.f, 0.f, 0.f, 0.f};
    float m_[2]   = {-3e38f, -3e38f};
    float lsum[2] = {0.f, 0.f};
    char* PsB = (char*)Ps + w * 4096;

    for (int t = 0; t < nt; ++t) {
        const int kv0 = t * KVB;
        const bool active = wave_active && (kv0 < kv_end_w);
        __syncthreads();
        {
            const fvec4* sk = (const fvec4*)(Kg + ((size_t)bh * Ss + kv0) * Dd);
            #pragma unroll
            for (int i = 0; i < 8; ++i) {
                int f = tid + 256 * i;
                int kr = f >> 5, d4 = f & 31;
                fvec4 v = sk[(size_t)kr * 32 + d4];
                u32x2 pr; pr[0] = pk2(v[0], v[1]); pr[1] = pk2(v[2], v[3]);
                int j = d4 >> 1;
                int js = (j & 8) | ((j & 7) ^ (kr & 7));
                *(u32x2*)((char*)Ks + kr * 256 + js * 16 + (d4 & 1) * 8) = pr;
            }
            const float* sv = Vg + ((size_t)bh * Ss + kv0) * Dd;
            #pragma unroll
            for (int i = 0; i < 2; ++i) {
                int idx = tid + 256 * i;
                int dt4 = idx & 31, kt4 = idx >> 5;
                fvec4 vv[4];
                #pragma unroll
                for (int jj = 0; jj < 4; ++jj)
                    vv[jj] = ((const fvec4*)(sv + (size_t)(kt4 * 4 + jj) * Dd))[dt4];
                #pragma unroll
                for (int jj = 0; jj < 4; ++jj) {
                    int d = dt4 * 4 + jj;
                    u32x2 pr;
                    pr[0] = pk2(vv[0][jj], vv[1][jj]);
                    pr[1] = pk2(vv[2][jj], vv[3][jj]);
                    int bo = d * 128 + ((kt4 >> 1) ^ (d & 7)) * 16 + (kt4 & 1) * 8;
                    *(u32x2*)((char*)Vt + bo) = pr;
                }
            }
        }
        __syncthreads();

        if (active) {
            f32x4 sa[2][4];
            #pragma unroll
            for (int t2 = 0; t2 < 2; ++t2)
                #pragma unroll
                for (int mt = 0; mt < 4; ++mt) sa[t2][mt] = (f32x4){0.f, 0.f, 0.f, 0.f};
            #pragma unroll
            for (int mt = 0; mt < 4; ++mt) {
                int row = mt * 16 + qc;
                bf16x8 kf[4];
                #pragma unroll
                for (int kc = 0; kc < 4; ++kc) {
                    int jb = kc * 4 + g;
                    int js = (jb & 8) | ((jb & 7) ^ (row & 7));
                    kf[kc] = *(const bf16x8*)((const char*)Ks + row * 256 + js * 16);
                }
                #pragma unroll
                for (int t2 = 0; t2 < 2; ++t2)
                    #pragma unroll
                    for (int kc = 0; kc < 4; ++kc)
                        sa[t2][mt] = __builtin_amdgcn_mfma_f32_16x16x32_bf16(
                            kf[kc], qf[t2][kc], sa[t2][mt], 0, 0, 0);
            }
            #pragma unroll
            for (int t2 = 0; t2 < 2; ++t2) {
                const int qrow = qw0 + 16 * t2 + qc;
                const bool full = (kv0 + KVB - 1) <= (qw0 + 16 * t2);
                if (!full) {
                    #pragma unroll
                    for (int mt = 0; mt < 4; ++mt)
                        #pragma unroll
                        for (int rr = 0; rr < 4; ++rr) {
                            int kk = kv0 + mt * 16 + g * 4 + rr;
                            if (kk > qrow) sa[t2][mt][rr] = -3e38f;
                        }
                }
                float tm = sa[t2][0][0];
                #pragma unroll
                for (int mt = 0; mt < 4; ++mt)
                    #pragma unroll
                    for (int rr = 0; rr < 4; ++rr) tm = fmaxf(tm, sa[t2][mt][rr]);
                tm = fmaxf(tm, __shfl_xor(tm, 16));
                tm = fmaxf(tm, __shfl_xor(tm, 32));
                if (__any(tm > m_[t2] + 8.0f)) {
                    float mnew = fmaxf(m_[t2], tm);
                    float al = exp2f(m_[t2] - mnew);
                    m_[t2] = mnew;
                    lsum[t2] *= al;
                    #pragma unroll
                    for (int rr = 0; rr < 4; ++rr) {
                        float alr = __shfl(al, g * 4 + rr);
                        #pragma unroll
                        for (int dt = 0; dt < 8; ++dt) o[t2][dt][rr] *= alr;
                    }
                }
                float mref = m_[t2];
                float ls = 0.f;
                int prow = t2 * 16 + qc;
                int pswz = (prow & 7) << 4;
                #pragma unroll
                for (int mt = 0; mt < 4; ++mt) {
                    f32x4 p;
                    #pragma unroll
                    for (int rr = 0; rr < 4; ++rr)
                        p[rr] = exp2f(sa[t2][mt][rr] - mref);
                    ls += (p[0] + p[1]) + (p[2] + p[3]);
                    u32x2 pw;
                    pw[0] = pk2(p[0], p[1]);
                    pw[1] = pk2(p[2], p[3]);
                    *(u32x2*)(PsB + ((prow * 128 + mt * 32 + g * 8) ^ pswz)) = pw;
                }
                lsum[t2] += ls;
            }
            bf16x8 ap[2][2];
            #pragma unroll
            for (int t2 = 0; t2 < 2; ++t2) {
                int prow = t2 * 16 + qc;
                int pswz = (prow & 7) << 4;
                #pragma unroll
                for (int c = 0; c < 2; ++c)
                    ap[t2][c] = *(const bf16x8*)(PsB + ((prow * 128 + c * 64 + g * 16) ^ pswz));
            }
            #pragma unroll
            for (int dt = 0; dt < 8; ++dt) {
                int d = dt * 16 + qc;
                #pragma unroll
                for (int c = 0; c < 2; ++c) {
                    int js = (c * 4 + g) ^ (d & 7);
                    bf16x8 bfv = *(const bf16x8*)((const char*)Vt + d * 128 + js * 16);
                    #pragma unroll
                    for (int t2 = 0; t2 < 2; ++t2)
                        o[t2][dt] = __builtin_amdgcn_mfma_f32_16x16x32_bf16(
                            ap[t2][c], bfv, o[t2][dt], 0, 0, 0);
                }
            }
        }
    }

    float inv_[2][4];
    #pragma unroll
    for (int t2 = 0; t2 < 2; ++t2) {
        float L = lsum[t2];
        L += __shfl_xor(L, 16);
        L += __shfl_xor(L, 32);
        #pragma unroll
        for (int rr = 0; rr < 4; ++rr) {
            float Lr = __shfl(L, g * 4 + rr);
            inv_[t2][rr] = 1.0f / Lr;
        }
    }
    bool needvm = (qw0 + 32 > len);
    float vmv[8];
    #pragma unroll
    for (int dt = 0; dt < 8; ++dt)
        vmv[dt] = needvm ? vmean[bh * Dd + dt * 16 + qc] : 0.f;
    #pragma unroll
    for (int t2 = 0; t2 < 2; ++t2)
        #pragma unroll
        for (int rr = 0; rr < 4; ++rr) {
            int rowg = qw0 + t2 * 16 + g * 4 + rr;
            float* orow = Og + ((size_t)bh * Ss + rowg) * Dd + qc;
            #pragma unroll
            for (int dt = 0; dt < 8; ++dt) {
                float val = o[t2][dt][rr] * inv_[t2][rr];
                if (rowg >= len) val = vmv[dt];
                orow[dt * 16] = val;
            }
        }
}

extern "C" void kernel_launch(void* const* d_in, const int* in_sizes, int n_in,
                              void* d_out, int out_size, void* d_ws, size_t ws_size,
                              hipStream_t stream) {
    const float* q  = (const float*)d_in[0];
    const float* k  = (const float*)d_in[1];
    const float* v  = (const float*)d_in[2];
    const int*   sl = (const int*)d_in[3];
    float* out = (float*)d_out;

    const size_t nElem = (size_t)Bb * Hh * Ss * Dd;
    const size_t need0 = nElem * 2 * 2 + 1024 * Dd * 4 + 64 * Dd * 4;

    if (ws_size >= need0) {
        short* Kbf  = (short*)d_ws;
        short* Vtb  = Kbf + nElem;
        float* part = (float*)(Vtb + nElem);
        float* vm   = part + 1024 * Dd;
        cvtk_kernel<<<dim3(8192), dim3(256), 0, stream>>>(k, Kbf);
        cvtv_kernel<<<dim3(1024), dim3(256), 0, stream>>>(v, Vtb, part);
        vcomb_kernel<<<dim3(Bb * Hh), dim3(128), 0, stream>>>(part, vm, 16);
        attn8_kernel<<<dim3(1024), dim3(512), 0, stream>>>(q, Kbf, Vtb, sl, vm, out);
    } else {
        float* part = (float*)d_ws;
        float* vm   = part + 512 * Dd;
        vpart_kernel<<<dim3(512), dim3(256), 0, stream>>>(v, part);
        vcomb_kernel<<<dim3(Bb * Hh), dim3(128), 0, stream>>>(part, vm, 8);
        attn_fb_kernel<<<dim3(1024), dim3(256), 0, stream>>>(q, k, v, sl, vm, out);
    }
}